// Round 1
// baseline (239.109 us; speedup 1.0000x reference)
//
#include <hip/hip_runtime.h>
#include <hip/hip_bf16.h>
#include <math.h>
#include <stdint.h>

// Problem constants: B=2, S=2048, D=1024, H=16, DK=64
constexpr int Bb = 2, Ss = 2048, Dd = 1024, Hh = 16;
constexpr int Mm = Bb * Ss;  // 4096 (GEMM M)
constexpr int Nn = Dd;       // 1024
constexpr int Kk = Dd;       // 1024
// fold 1/sqrt(DK) and log2(e) into Q so the softmax uses exp2
constexpr float QSCALE = 0.125f * 1.44269504088896340736f;

typedef unsigned short ushort_t;
typedef __attribute__((ext_vector_type(8))) short bf16x8;   // A/B frag (4 VGPRs)
typedef __attribute__((ext_vector_type(4))) float f32x4;    // 16x16 C/D frag

#if __has_builtin(__builtin_amdgcn_exp2f)
#define EXP2F(x) __builtin_amdgcn_exp2f(x)
#else
#define EXP2F(x) exp2f(x)
#endif

__device__ __forceinline__ ushort_t f2bf(float f) {  // round-to-nearest-even
  union { float f; unsigned u; } v; v.f = f;
  return (ushort_t)((v.u + 0x7fff + ((v.u >> 16) & 1)) >> 16);
}

// async global->LDS, 16B per lane; LDS dest is wave-uniform base + lane*16
__device__ __forceinline__ void load16_lds(const void* g, void* l) {
  __builtin_amdgcn_global_load_lds(
      (const __attribute__((address_space(1))) void*)(uintptr_t)g,
      (__attribute__((address_space(3))) void*)(uint32_t)(uintptr_t)l, 16, 0, 0);
}

// ---------------------------------------------------------------------------
// Merged prep pass (one dispatch):
//  blocks [0, 12288): fp32->bf16 convert of q,k,v  (z = bid/4096)
//  blocks [12288, 13312): W [K][N] fp32 -> Wt [N][K] bf16 transpose
// Independent workloads; merging saves a launch + inter-dispatch gap.
// ---------------------------------------------------------------------------
__global__ __launch_bounds__(256) void prep(
    const float* __restrict__ q, const float* __restrict__ k,
    const float* __restrict__ v, ushort_t* __restrict__ qkvb,
    const float* __restrict__ Wq, const float* __restrict__ Wk,
    const float* __restrict__ Wv, const float* __restrict__ Wo,
    ushort_t* __restrict__ Wt) {
  const int bid = blockIdx.x;
  const int tid = threadIdx.x;
  if (bid < 12288) {  // ---- convert q/k/v ----
    const int z = bid >> 12, xi = bid & 4095;
    const float* src = (z == 0) ? q : (z == 1) ? k : v;
    ushort_t* dst = qkvb + (size_t)z * Mm * Kk;
    const size_t idx = ((size_t)xi * 256 + tid) * 4;
    const float4 val = *(const float4*)(src + idx);
    ushort4 o;
    o.x = f2bf(val.x); o.y = f2bf(val.y); o.z = f2bf(val.z); o.w = f2bf(val.w);
    *(ushort4*)(dst + idx) = o;
    return;
  }
  // ---- transpose weights ----
  const int bid2 = bid - 12288;
  const int z = bid2 >> 8, rem = bid2 & 255;
  const float* W = (z == 0) ? Wq : (z == 1) ? Wk : (z == 2) ? Wv : Wo;
  ushort_t* out = Wt + (size_t)z * Kk * Nn;
  __shared__ float t[64][65];
  const int n0 = (rem & 15) * 64, k0 = (rem >> 4) * 64;
  const int lr = tid >> 4, lc = (tid & 15) * 4;
#pragma unroll
  for (int i = 0; i < 4; i++) {
    const int r = lr + i * 16;
    const float4 vv = *(const float4*)(W + (size_t)(k0 + r) * Nn + n0 + lc);
    t[r][lc] = vv.x; t[r][lc + 1] = vv.y; t[r][lc + 2] = vv.z; t[r][lc + 3] = vv.w;
  }
  __syncthreads();
  const int n = tid >> 2, kc = (tid & 3) * 16;
  ushort_t tmp[16];
#pragma unroll
  for (int j = 0; j < 16; j++) tmp[j] = f2bf(t[kc + j][n]);
  ushort_t* op = out + (size_t)(n0 + n) * Kk + k0 + kc;
  ((uint4*)op)[0] = ((uint4*)tmp)[0];
  ((uint4*)op)[1] = ((uint4*)tmp)[1];
}

// ---------------------------------------------------------------------------
// Vp [B*S][D] bf16 -> Vt [B][D][S] bf16  (PV A-operand wants V^T rows)
// ---------------------------------------------------------------------------
__global__ __launch_bounds__(256) void transpose_v(
    const ushort_t* __restrict__ Vp, ushort_t* __restrict__ Vt) {
  __shared__ ushort_t t[64][68];
  const int tid = threadIdx.x;
  const int s0 = blockIdx.x * 64, h = blockIdx.y, b = blockIdx.z;
  const int lr = tid >> 4, lc = (tid & 15) * 4;
#pragma unroll
  for (int i = 0; i < 4; i++) {
    const int r = lr + i * 16;
    const ushort4 v =
        *(const ushort4*)(Vp + (size_t)(b * Ss + s0 + r) * Dd + h * 64 + lc);
    *(ushort4*)&t[r][lc] = v;
  }
  __syncthreads();
  const int d = tid >> 2, sc = (tid & 3) * 16;
  ushort_t tmp[16];
#pragma unroll
  for (int j = 0; j < 16; j++) tmp[j] = t[sc + j][d];
  ushort_t* op = Vt + ((size_t)b * Dd + h * 64 + d) * Ss + s0 + sc;
  ((uint4*)op)[0] = ((uint4*)tmp)[0];
  ((uint4*)op)[1] = ((uint4*)tmp)[1];
}

// ---------------------------------------------------------------------------
// bf16 MFMA GEMM, m97 recipe: BM=128, BK=32, global_load_lds width=16,
// 16x16x32 MFMA — the r7 measured-best core (32x32 variant cost +11us; fused
// fp32-A staging cost +16us via doubled HBM re-fetch — both reverted).
// A [M][K] bf16, Wt [N][K] bf16 (pre-transposed), out = (A@W + bias)*scale.
// ---------------------------------------------------------------------------
template <int BN, bool OUT_BF16>
__global__ __launch_bounds__(256) void gemm_mfma(
    const ushort_t* __restrict__ Abase, size_t a_stride,
    const ushort_t* __restrict__ Wbase, size_t w_stride,
    const float* __restrict__ bias0, const float* __restrict__ bias1,
    const float* __restrict__ bias2, void* __restrict__ Cbase, size_t c_stride,
    float scale_z0) {
  constexpr int BM = 128, BK = 32;
  constexpr int WM = (BN == 128) ? 64 : 32;  // wave tile
  constexpr int MT_ = WM / 16, NT_ = 4;      // WN = 64 always
  __shared__ ushort_t As[BM * BK];
  __shared__ ushort_t Bs[BN * BK];
  const int tid = threadIdx.x, lane = tid & 63, wid = tid >> 6;
  const int z = blockIdx.z;
  const ushort_t* A = Abase + (size_t)z * a_stride;
  const ushort_t* Wt = Wbase + (size_t)z * w_stride;
  const float* bias = (z == 0) ? bias0 : (z == 1) ? bias1 : bias2;
  const float sc = (z == 0) ? scale_z0 : 1.0f;
  const int m0 = blockIdx.y * BM, n0 = blockIdx.x * BN;
  const int wm = (BN == 128) ? (wid >> 1) * 64 : wid * 32;
  const int wn = (BN == 128) ? (wid & 1) * 64 : 0;
  const int quad = lane >> 4, r16 = lane & 15;
  const int srow = lane >> 2;        // staging: 16 rows/inst
  const int scol = (lane & 3) * 8;   // 4 lanes x 16B per 64B row

  f32x4 acc[MT_][NT_];
#pragma unroll
  for (int m = 0; m < MT_; m++)
#pragma unroll
    for (int n = 0; n < NT_; n++) acc[m][n] = f32x4{0.f, 0.f, 0.f, 0.f};

  for (int k0 = 0; k0 < Kk; k0 += BK) {
    __syncthreads();
#pragma unroll
    for (int i = 0; i < BM / 64; i++) {
      const int I = wid * (BM / 64) + i;
      load16_lds(A + (size_t)(m0 + I * 16 + srow) * Kk + k0 + scol, As + I * 512);
    }
#pragma unroll
    for (int i = 0; i < BN / 64; i++) {
      const int I = wid * (BN / 64) + i;
      load16_lds(Wt + (size_t)(n0 + I * 16 + srow) * Kk + k0 + scol, Bs + I * 512);
    }
    __syncthreads();
    bf16x8 af[MT_], bfr[NT_];
#pragma unroll
    for (int m = 0; m < MT_; m++)
      af[m] = *(const bf16x8*)(As + (wm + m * 16 + r16) * BK + quad * 8);
#pragma unroll
    for (int n = 0; n < NT_; n++)
      bfr[n] = *(const bf16x8*)(Bs + (wn + n * 16 + r16) * BK + quad * 8);
#pragma unroll
    for (int m = 0; m < MT_; m++)
#pragma unroll
      for (int n = 0; n < NT_; n++)
        acc[m][n] =
            __builtin_amdgcn_mfma_f32_16x16x32_bf16(af[m], bfr[n], acc[m][n], 0, 0, 0);
  }

  // epilogue: C/D layout col=lane&15, row=quad*4+reg
#pragma unroll
  for (int m = 0; m < MT_; m++) {
#pragma unroll
    for (int n = 0; n < NT_; n++) {
      const int gc = n0 + wn + n * 16 + r16;
      const float bv = bias[gc];
#pragma unroll
      for (int r = 0; r < 4; r++) {
        const int gr = m0 + wm + m * 16 + quad * 4 + r;
        const float v = (acc[m][n][r] + bv) * sc;
        if (OUT_BF16)
          ((ushort_t*)Cbase)[(size_t)z * c_stride + (size_t)gr * Nn + gc] = f2bf(v);
        else
          ((float*)Cbase)[(size_t)z * c_stride + (size_t)gr * Nn + gc] = v;
      }
    }
  }
}

// ---------------------------------------------------------------------------
// MFMA flash attention v4: software-pipelined staging.
// v3 (65 us, MfmaUtil 21%) was latency-bound: per K-tile
// {barrier -> global_load_lds -> vmcnt(0)+barrier -> compute} serially ate a
// full L2/HBM latency with only 4 waves/SIMD to hide it.
// v4: double-buffered Ks/Vts, prologue-staged; each iter issues tile t+1's
// loads BEFORE computing tile t, waits counted vmcnt(4) (t+1's 4 loads stay
// in flight across both raw s_barriers).  Ps shrunk 72->64 stride with an
// even-granule XOR swizzle so total LDS = 40960 B (exactly 4 blocks/CU).
// XCD-bijective block swizzle: each XCD owns 4 contiguous (b,h) groups so
// K/V (512 KB per group) stay L2-resident per XCD.
// ---------------------------------------------------------------------------
__global__ __launch_bounds__(256) void flash_mfma(
    const ushort_t* __restrict__ Qp, const ushort_t* __restrict__ Kp,
    const ushort_t* __restrict__ Vt, ushort_t* __restrict__ Xp) {
  __shared__ ushort_t Ks[2][64 * 64];   // [key][d], chunk-swizzled, dbuf
  __shared__ ushort_t Vts[2][64 * 64];  // [d][key], chunk-swizzled, dbuf
  __shared__ ushort_t Ps[64 * 64];      // [qrow][key], stride 64, XOR-swz
  const int tid = threadIdx.x, lane = tid & 63, wid = tid >> 6;
  // XCD-bijective swizzle: nwg=1024, 8 XCDs, 128 blocks/XCD = 4 (b,h) groups
  const int lid = blockIdx.x + (blockIdx.y << 5) + (blockIdx.z << 9);
  const int swzb = ((lid & 7) << 7) + (lid >> 3);
  const int qt = swzb & 31, h = (swzb >> 5) & 15, b = swzb >> 9;
  const int quad = lane >> 4, r16 = lane & 15;
  const int row8 = lane >> 3;                       // staging row in 8-row chunk
  const int colsw = ((lane & 7) ^ (row8 & 7)) * 8;  // swizzled source col (u16)
  const int swz = r16 & 7;                          // read-side swizzle key
  const int psw2 = (r16 & 7) * 2;                   // Ps granule-4 XOR key (even)

  const int qrow = wid * 16 + r16;  // this lane's qrow within the 64-tile
  const ushort_t* Qg = Qp + ((size_t)(b * Ss + qt * 64)) * Dd + h * 64;
  const ushort_t* Kg = Kp + ((size_t)b * Ss) * Dd + h * 64;
  const ushort_t* Vg = Vt + ((size_t)b * Dd + h * 64) * Ss;  // rows d, stride S

  // Q fragments in registers (B-operand: n=qrow, k=d contiguous)
  bf16x8 qf[2];
#pragma unroll
  for (int ks = 0; ks < 2; ks++)
    qf[ks] = *(const bf16x8*)(Qg + (size_t)qrow * Dd + ks * 32 + quad * 8);

  f32x4 acc[4];  // Ot: m=d-tile(4), n=qrow
  float rs = 0.f;
#pragma unroll
  for (int mt = 0; mt < 4; mt++) acc[mt] = f32x4{0.f, 0.f, 0.f, 0.f};

  // stage tile kt into LDS buffer bsel (4 global_load_lds per wave)
  auto stage = [&](int kt, int bsel) {
#pragma unroll
    for (int i = 0; i < 2; i++) {
      const int I = wid * 2 + i;
      load16_lds(Kg + (size_t)(kt * 64 + I * 8 + row8) * Dd + colsw,
                 &Ks[bsel][I * 512]);
      load16_lds(Vg + (size_t)(I * 8 + row8) * Ss + kt * 64 + colsw,
                 &Vts[bsel][I * 512]);
    }
  };

  // prologue: stage tile 0; drain the 2 qf loads (leave stage 0 in flight)
  stage(0, 0);
  asm volatile("s_waitcnt vmcnt(4)" ::: "memory");

  for (int kt = 0; kt < Ss / 64; kt++) {
    const int cur = kt & 1;
    if (kt + 1 < Ss / 64) {
      // issue next tile into the other buffer (safe: end-of-(kt-1) barrier
      // guarantees every wave finished reading it), then wait ONLY for tile
      // kt's 4 loads — tile kt+1's stay in flight across both barriers.
      stage(kt + 1, cur ^ 1);
      asm volatile("s_waitcnt vmcnt(4)\n\ts_barrier" ::: "memory");
    } else {
      asm volatile("s_waitcnt vmcnt(0)\n\ts_barrier" ::: "memory");
    }

    // St[key][qrow] = K Q^T for this wave's 16 qrows x 64 keys
    f32x4 sacc[4];
#pragma unroll
    for (int mm = 0; mm < 4; mm++) sacc[mm] = f32x4{0.f, 0.f, 0.f, 0.f};
    __builtin_amdgcn_s_setprio(1);
#pragma unroll
    for (int ks = 0; ks < 2; ks++) {
      const int ko = ((ks * 4 + quad) ^ swz) * 8;
      bf16x8 kf[4];
#pragma unroll
      for (int mm = 0; mm < 4; mm++)
        kf[mm] = *(const bf16x8*)(&Ks[cur][(mm * 16 + r16) * 64 + ko]);
#pragma unroll
      for (int mm = 0; mm < 4; mm++)
        sacc[mm] = __builtin_amdgcn_mfma_f32_16x16x32_bf16(
            kf[mm], qf[ks], sacc[mm], 0, 0, 0);
    }
    __builtin_amdgcn_s_setprio(0);

    // p = exp2(s); row-sum partials; packed 8B P write (XOR-swizzled granule)
#pragma unroll
    for (int mm = 0; mm < 4; mm++) {
      float p0 = EXP2F(sacc[mm][0]), p1 = EXP2F(sacc[mm][1]);
      float p2 = EXP2F(sacc[mm][2]), p3 = EXP2F(sacc[mm][3]);
      rs += (p0 + p1) + (p2 + p3);
      union { __hip_bfloat162 hh; unsigned u; } lo, hi;
      lo.hh = __float22bfloat162_rn(make_float2(p0, p1));
      hi.hh = __float22bfloat162_rn(make_float2(p2, p3));
      *(uint2*)(Ps + qrow * 64 + (((mm * 4 + quad) ^ psw2) << 2)) =
          make_uint2(lo.u, hi.u);
    }
    // P rows wave-private: in-wave lgkmcnt ordering suffices, no barrier.

    // Ot[d][qrow] += V^T P^T
    __builtin_amdgcn_s_setprio(1);
#pragma unroll
    for (int ks = 0; ks < 2; ks++) {
      const int ko = ((ks * 4 + quad) ^ swz) * 8;
      bf16x8 vf[4];
#pragma unroll
      for (int mt = 0; mt < 4; mt++)
        vf[mt] = *(const bf16x8*)(&Vts[cur][(mt * 16 + r16) * 64 + ko]);
      const bf16x8 pf = *(const bf16x8*)(
          Ps + qrow * 64 + ((((ks * 4 + quad) << 1) ^ psw2) << 2));
#pragma unroll
      for (int mt = 0; mt < 4; mt++)
        acc[mt] = __builtin_amdgcn_mfma_f32_16x16x32_bf16(
            vf[mt], pf, acc[mt], 0, 0, 0);
    }
    __builtin_amdgcn_s_setprio(0);

    // all LDS reads of buf[cur] were consumed above (compiler lgkmcnt waits);
    // this barrier licenses next iter's stage into buf[cur].
    asm volatile("s_barrier" ::: "memory");
  }

  // full row sum: combine the 4 key-quads (lanes with same r16)
  rs += __shfl_xor(rs, 16, 64);
  rs += __shfl_xor(rs, 32, 64);
  const float inv = 1.0f / rs;

  // write X: Ot C-layout: d = mt*16+quad*4+r (consecutive r), qrow = r16
#pragma unroll
  for (int mt = 0; mt < 4; mt++) {
    ushort4 o;
    o.x = f2bf(acc[mt][0] * inv);
    o.y = f2bf(acc[mt][1] * inv);
    o.z = f2bf(acc[mt][2] * inv);
    o.w = f2bf(acc[mt][3] * inv);
    *(ushort4*)(Xp + (size_t)(b * Ss + qt * 64 + qrow) * Dd +
                h * 64 + mt * 16 + quad * 4) = o;
  }
}

// ---------------------------------------------------------------------------
extern "C" void kernel_launch(void* const* d_in, const int* in_sizes, int n_in,
                              void* d_out, int out_size, void* d_ws,
                              size_t ws_size, hipStream_t stream) {
  const float* q  = (const float*)d_in[0];
  const float* k  = (const float*)d_in[1];
  const float* v  = (const float*)d_in[2];
  const float* Wq = (const float*)d_in[3];
  const float* bq = (const float*)d_in[4];
  const float* Wk = (const float*)d_in[5];
  const float* bk = (const float*)d_in[6];
  const float* Wv = (const float*)d_in[7];
  const float* bv = (const float*)d_in[8];
  const float* Wo = (const float*)d_in[9];
  const float* bo = (const float*)d_in[10];

  ushort_t* ws = (ushort_t*)d_ws;
  const size_t MD = (size_t)Mm * Kk;  // 4,194,304
  const size_t KN = (size_t)Kk * Nn;  // 1,048,576
  ushort_t* qkvb = ws;                // 3*MD   bf16 inputs
  ushort_t* Wt   = ws + 3 * MD;       // 4*KN   transposed weights
  ushort_t* QKVp = Wt + 4 * KN;       // 3*MD   Q,K,V projections
  ushort_t* Vtp  = QKVp + 3 * MD;     // MD     V^T per head
  ushort_t* Xp   = qkvb;              // reuse: qkvb dead after QKV GEMMs

  prep<<<dim3(13312), 256, 0, stream>>>(q, k, v, qkvb, Wq, Wk, Wv, Wo, Wt);
  gemm_mfma<128, true><<<dim3(Nn / 128, Mm / 128, 3), 256, 0, stream>>>(
      qkvb, MD, Wt, KN, bq, bk, bv, QKVp, MD, QSCALE);
  transpose_v<<<dim3(Ss / 64, Hh, Bb), 256, 0, stream>>>(QKVp + 2 * MD, Vtp);
  flash_mfma<<<dim3(Ss / 64, Hh, Bb), 256, 0, stream>>>(QKVp, QKVp + MD, Vtp, Xp);
  gemm_mfma<64, false><<<dim3(Nn / 64, Mm / 128, 1), 256, 0, stream>>>(
      Xp, 0, Wt + 3 * KN, 0, bo, bo, bo, d_out, 0, 1.0f);
}

// Round 2
// 237.345 us; speedup vs baseline: 1.0074x; 1.0074x over previous
//
#include <hip/hip_runtime.h>
#include <hip/hip_bf16.h>
#include <math.h>
#include <stdint.h>

// Problem constants: B=2, S=2048, D=1024, H=16, DK=64
constexpr int Bb = 2, Ss = 2048, Dd = 1024, Hh = 16;
constexpr int Mm = Bb * Ss;  // 4096 (GEMM M)
constexpr int Nn = Dd;       // 1024
constexpr int Kk = Dd;       // 1024
// fold 1/sqrt(DK) and log2(e) into Q so the softmax uses exp2
constexpr float QSCALE = 0.125f * 1.44269504088896340736f;

typedef unsigned short ushort_t;
typedef __attribute__((ext_vector_type(8))) short bf16x8;   // K=32 A/B frag
typedef __attribute__((ext_vector_type(4))) short bf16x4;   // K=16 A/B frag
typedef __attribute__((ext_vector_type(4))) float f32x4;    // 16x16 C/D frag

#if __has_builtin(__builtin_amdgcn_exp2f)
#define EXP2F(x) __builtin_amdgcn_exp2f(x)
#else
#define EXP2F(x) exp2f(x)
#endif

__device__ __forceinline__ ushort_t f2bf(float f) {  // round-to-nearest-even
  union { float f; unsigned u; } v; v.f = f;
  return (ushort_t)((v.u + 0x7fff + ((v.u >> 16) & 1)) >> 16);
}

__device__ __forceinline__ f32x4 mfma16(bf16x4 a, bf16x4 b, f32x4 c) {
#if __has_builtin(__builtin_amdgcn_mfma_f32_16x16x16bf16_1k)
  return __builtin_amdgcn_mfma_f32_16x16x16bf16_1k(a, b, c, 0, 0, 0);
#else
  asm("v_mfma_f32_16x16x16_bf16 %0, %1, %2, %0" : "+v"(c) : "v"(a), "v"(b));
  return c;
#endif
}

// async global->LDS, 16B per lane; LDS dest is wave-uniform base + lane*16
__device__ __forceinline__ void load16_lds(const void* g, void* l) {
  __builtin_amdgcn_global_load_lds(
      (const __attribute__((address_space(1))) void*)(uintptr_t)g,
      (__attribute__((address_space(3))) void*)(uint32_t)(uintptr_t)l, 16, 0, 0);
}

// ---------------------------------------------------------------------------
// Merged prep pass (one dispatch):
//  blocks [0, 12288): fp32->bf16 convert of q,k,v  (z = bid/4096)
//  blocks [12288, 13312): W [K][N] fp32 -> Wt [N][K] bf16 transpose
// ---------------------------------------------------------------------------
__global__ __launch_bounds__(256) void prep(
    const float* __restrict__ q, const float* __restrict__ k,
    const float* __restrict__ v, ushort_t* __restrict__ qkvb,
    const float* __restrict__ Wq, const float* __restrict__ Wk,
    const float* __restrict__ Wv, const float* __restrict__ Wo,
    ushort_t* __restrict__ Wt) {
  const int bid = blockIdx.x;
  const int tid = threadIdx.x;
  if (bid < 12288) {  // ---- convert q/k/v ----
    const int z = bid >> 12, xi = bid & 4095;
    const float* src = (z == 0) ? q : (z == 1) ? k : v;
    ushort_t* dst = qkvb + (size_t)z * Mm * Kk;
    const size_t idx = ((size_t)xi * 256 + tid) * 4;
    const float4 val = *(const float4*)(src + idx);
    ushort4 o;
    o.x = f2bf(val.x); o.y = f2bf(val.y); o.z = f2bf(val.z); o.w = f2bf(val.w);
    *(ushort4*)(dst + idx) = o;
    return;
  }
  // ---- transpose weights ----
  const int bid2 = bid - 12288;
  const int z = bid2 >> 8, rem = bid2 & 255;
  const float* W = (z == 0) ? Wq : (z == 1) ? Wk : (z == 2) ? Wv : Wo;
  ushort_t* out = Wt + (size_t)z * Kk * Nn;
  __shared__ float t[64][65];
  const int n0 = (rem & 15) * 64, k0 = (rem >> 4) * 64;
  const int lr = tid >> 4, lc = (tid & 15) * 4;
#pragma unroll
  for (int i = 0; i < 4; i++) {
    const int r = lr + i * 16;
    const float4 vv = *(const float4*)(W + (size_t)(k0 + r) * Nn + n0 + lc);
    t[r][lc] = vv.x; t[r][lc + 1] = vv.y; t[r][lc + 2] = vv.z; t[r][lc + 3] = vv.w;
  }
  __syncthreads();
  const int n = tid >> 2, kc = (tid & 3) * 16;
  ushort_t tmp[16];
#pragma unroll
  for (int j = 0; j < 16; j++) tmp[j] = f2bf(t[kc + j][n]);
  ushort_t* op = out + (size_t)(n0 + n) * Kk + k0 + kc;
  ((uint4*)op)[0] = ((uint4*)tmp)[0];
  ((uint4*)op)[1] = ((uint4*)tmp)[1];
}

// ---------------------------------------------------------------------------
// Vp [B*S][D] bf16 -> Vt [B][D][S] bf16  (PV A-operand wants V^T rows)
// ---------------------------------------------------------------------------
__global__ __launch_bounds__(256) void transpose_v(
    const ushort_t* __restrict__ Vp, ushort_t* __restrict__ Vt) {
  __shared__ ushort_t t[64][68];
  const int tid = threadIdx.x;
  const int s0 = blockIdx.x * 64, h = blockIdx.y, b = blockIdx.z;
  const int lr = tid >> 4, lc = (tid & 15) * 4;
#pragma unroll
  for (int i = 0; i < 4; i++) {
    const int r = lr + i * 16;
    const ushort4 v =
        *(const ushort4*)(Vp + (size_t)(b * Ss + s0 + r) * Dd + h * 64 + lc);
    *(ushort4*)&t[r][lc] = v;
  }
  __syncthreads();
  const int d = tid >> 2, sc = (tid & 3) * 16;
  ushort_t tmp[16];
#pragma unroll
  for (int j = 0; j < 16; j++) tmp[j] = t[sc + j][d];
  ushort_t* op = Vt + ((size_t)b * Dd + h * 64 + d) * Ss + s0 + sc;
  ((uint4*)op)[0] = ((uint4*)tmp)[0];
  ((uint4*)op)[1] = ((uint4*)tmp)[1];
}

// ---------------------------------------------------------------------------
// bf16 MFMA GEMM, m97 recipe (unchanged, measured-best for this size).
// ---------------------------------------------------------------------------
template <int BN, bool OUT_BF16>
__global__ __launch_bounds__(256) void gemm_mfma(
    const ushort_t* __restrict__ Abase, size_t a_stride,
    const ushort_t* __restrict__ Wbase, size_t w_stride,
    const float* __restrict__ bias0, const float* __restrict__ bias1,
    const float* __restrict__ bias2, void* __restrict__ Cbase, size_t c_stride,
    float scale_z0) {
  constexpr int BM = 128, BK = 32;
  constexpr int WM = (BN == 128) ? 64 : 32;  // wave tile
  constexpr int MT_ = WM / 16, NT_ = 4;      // WN = 64 always
  __shared__ ushort_t As[BM * BK];
  __shared__ ushort_t Bs[BN * BK];
  const int tid = threadIdx.x, lane = tid & 63, wid = tid >> 6;
  const int z = blockIdx.z;
  const ushort_t* A = Abase + (size_t)z * a_stride;
  const ushort_t* Wt = Wbase + (size_t)z * w_stride;
  const float* bias = (z == 0) ? bias0 : (z == 1) ? bias1 : bias2;
  const float sc = (z == 0) ? scale_z0 : 1.0f;
  const int m0 = blockIdx.y * BM, n0 = blockIdx.x * BN;
  const int wm = (BN == 128) ? (wid >> 1) * 64 : wid * 32;
  const int wn = (BN == 128) ? (wid & 1) * 64 : 0;
  const int quad = lane >> 4, r16 = lane & 15;
  const int srow = lane >> 2;        // staging: 16 rows/inst
  const int scol = (lane & 3) * 8;   // 4 lanes x 16B per 64B row

  f32x4 acc[MT_][NT_];
#pragma unroll
  for (int m = 0; m < MT_; m++)
#pragma unroll
    for (int n = 0; n < NT_; n++) acc[m][n] = f32x4{0.f, 0.f, 0.f, 0.f};

  for (int k0 = 0; k0 < Kk; k0 += BK) {
    __syncthreads();
#pragma unroll
    for (int i = 0; i < BM / 64; i++) {
      const int I = wid * (BM / 64) + i;
      load16_lds(A + (size_t)(m0 + I * 16 + srow) * Kk + k0 + scol, As + I * 512);
    }
#pragma unroll
    for (int i = 0; i < BN / 64; i++) {
      const int I = wid * (BN / 64) + i;
      load16_lds(Wt + (size_t)(n0 + I * 16 + srow) * Kk + k0 + scol, Bs + I * 512);
    }
    __syncthreads();
    bf16x8 af[MT_], bfr[NT_];
#pragma unroll
    for (int m = 0; m < MT_; m++)
      af[m] = *(const bf16x8*)(As + (wm + m * 16 + r16) * BK + quad * 8);
#pragma unroll
    for (int n = 0; n < NT_; n++)
      bfr[n] = *(const bf16x8*)(Bs + (wn + n * 16 + r16) * BK + quad * 8);
#pragma unroll
    for (int m = 0; m < MT_; m++)
#pragma unroll
      for (int n = 0; n < NT_; n++)
        acc[m][n] =
            __builtin_amdgcn_mfma_f32_16x16x32_bf16(af[m], bfr[n], acc[m][n], 0, 0, 0);
  }

  // epilogue: C/D layout col=lane&15, row=quad*4+reg
#pragma unroll
  for (int m = 0; m < MT_; m++) {
#pragma unroll
    for (int n = 0; n < NT_; n++) {
      const int gc = n0 + wn + n * 16 + r16;
      const float bv = bias[gc];
#pragma unroll
      for (int r = 0; r < 4; r++) {
        const int gr = m0 + wm + m * 16 + quad * 4 + r;
        const float v = (acc[m][n][r] + bv) * sc;
        if (OUT_BF16)
          ((ushort_t*)Cbase)[(size_t)z * c_stride + (size_t)gr * Nn + gc] = f2bf(v);
        else
          ((float*)Cbase)[(size_t)z * c_stride + (size_t)gr * Nn + gc] = v;
      }
    }
  }
}

// ---------------------------------------------------------------------------
// MFMA flash attention v5: key-partitioned waves (LDS-traffic rewrite).
// v4 evidence: LDS-BW-bound (~96 KB LDS traffic per block-tile; MfmaUtil 21%,
// HBM 4%) — all 4 waves re-read identical K/V fragments, P round-tripped LDS.
// v5: wave w owns keys [16w,16w+16) of each 64-key tile; all 64 qrows' Q
// fragments live in registers (loaded once).  kf: 2 reads/wave (was 8);
// vf: 4 b64 reads/wave; P stays IN REGISTERS: swapped QK^T's C-layout
// (key=quad*4+reg, qrow=r16) IS the K=16 PV B-fragment layout exactly.
// LDS traffic 96 -> 32 KB per block-tile.  Cost: once-per-block cross-wave
// tree reduction of partial O + rowsums through LDS (padded rows, 68 f32).
// Staging dbuf + counted vmcnt + XCD swizzle kept from v4.
// ---------------------------------------------------------------------------
__global__ __launch_bounds__(256, 3) void flash_mfma(
    const ushort_t* __restrict__ Qp, const ushort_t* __restrict__ Kp,
    const ushort_t* __restrict__ Vt, ushort_t* __restrict__ Xp) {
  // union: staging (Ks[2][4096] + Vts[2][4096] u16 = 32768 B) vs
  // end-reduction (2 slots x 64 lanes x 68 f32 = 34816 B)
  __shared__ __align__(16) char smem[2 * 64 * 68 * 4];
  ushort_t* KsU = (ushort_t*)smem;       // [2][64*64]
  ushort_t* VtsU = KsU + 2 * 4096;       // [2][64*64]

  const int tid = threadIdx.x, lane = tid & 63, wid = tid >> 6;
  // XCD-bijective swizzle: nwg=1024, 8 XCDs, 128 blocks/XCD = 4 (b,h) groups
  const int lid = blockIdx.x + (blockIdx.y << 5) + (blockIdx.z << 9);
  const int swzb = ((lid & 7) << 7) + (lid >> 3);
  const int qt = swzb & 31, h = (swzb >> 5) & 15, b = swzb >> 9;
  const int quad = lane >> 4, r16 = lane & 15;
  const int row8 = lane >> 3;                       // staging row in 8-row chunk
  const int colsw = ((lane & 7) ^ row8) * 8;        // swizzled source col (u16)
  const int swz = r16 & 7;                          // read-side swizzle key

  const ushort_t* Qg = Qp + ((size_t)(b * Ss + qt * 64)) * Dd + h * 64;
  const ushort_t* Kg = Kp + ((size_t)b * Ss) * Dd + h * 64;
  const ushort_t* Vg = Vt + ((size_t)b * Dd + h * 64) * Ss;  // rows d, stride S

  // Q fragments for ALL 64 qrows (B-operand): qf[ks][n] = Q[n*16+r16][ks*32+quad*8..]
  bf16x8 qf[2][4];
#pragma unroll
  for (int n = 0; n < 4; n++)
#pragma unroll
    for (int ks = 0; ks < 2; ks++)
      qf[ks][n] = *(const bf16x8*)(Qg + (size_t)(n * 16 + r16) * Dd + ks * 32 + quad * 8);

  // LDS read offsets (u16 units), loop-invariant
  const uint32_t kbase = (uint32_t)(wid * 16 + r16) * 64;
  const uint32_t koff0 = kbase + (uint32_t)(((0 * 4 + quad) ^ swz) << 3);
  const uint32_t koff1 = kbase + (uint32_t)(((1 * 4 + quad) ^ swz) << 3);
  const int vG = wid * 2 + (quad >> 1);
  const uint32_t vcol = (uint32_t)(((vG ^ swz) << 3) + (quad & 1) * 4);

  f32x4 acc[4][4];  // [mt d-tile][n qrow-tile], partial over this wave's keys
#pragma unroll
  for (int mt = 0; mt < 4; mt++)
#pragma unroll
    for (int n = 0; n < 4; n++) acc[mt][n] = f32x4{0.f, 0.f, 0.f, 0.f};
  float rsn[4] = {0.f, 0.f, 0.f, 0.f};  // rowsum partials per qrow-tile

  auto stage = [&](int kt, int bsel) {
#pragma unroll
    for (int i = 0; i < 2; i++) {
      const int I = wid * 2 + i;
      load16_lds(Kg + (size_t)(kt * 64 + I * 8 + row8) * Dd + colsw,
                 KsU + bsel * 4096 + I * 512);
      load16_lds(Vg + (size_t)(I * 8 + row8) * Ss + kt * 64 + colsw,
                 VtsU + bsel * 4096 + I * 512);
    }
  };

  // prologue: qf loads above are in flight; stage tile 0; drain qf only
  stage(0, 0);
  asm volatile("s_waitcnt vmcnt(4)" ::: "memory");

  for (int kt = 0; kt < Ss / 64; kt++) {
    const int cur = kt & 1;
    if (kt + 1 < Ss / 64) {
      stage(kt + 1, cur ^ 1);  // 4 more loads in flight across both barriers
      asm volatile("s_waitcnt vmcnt(4)\n\ts_barrier" ::: "memory");
    } else {
      asm volatile("s_waitcnt vmcnt(0)\n\ts_barrier" ::: "memory");
    }
    const ushort_t* Kc = KsU + cur * 4096;
    const ushort_t* Vc = VtsU + cur * 4096;

    // QK^T: this wave's 16 keys x all 64 qrows
    const bf16x8 kf0 = *(const bf16x8*)(Kc + koff0);
    const bf16x8 kf1 = *(const bf16x8*)(Kc + koff1);
    f32x4 sacc[4];
#pragma unroll
    for (int n = 0; n < 4; n++) sacc[n] = f32x4{0.f, 0.f, 0.f, 0.f};
    __builtin_amdgcn_s_setprio(1);
#pragma unroll
    for (int n = 0; n < 4; n++)
      sacc[n] = __builtin_amdgcn_mfma_f32_16x16x32_bf16(kf0, qf[0][n], sacc[n], 0, 0, 0);
#pragma unroll
    for (int n = 0; n < 4; n++)
      sacc[n] = __builtin_amdgcn_mfma_f32_16x16x32_bf16(kf1, qf[1][n], sacc[n], 0, 0, 0);
    __builtin_amdgcn_s_setprio(0);

    // softmax: P stays in registers; C-layout == K=16 B-fragment layout
    bf16x4 pf[4];
#pragma unroll
    for (int n = 0; n < 4; n++) {
      const float p0 = EXP2F(sacc[n][0]), p1 = EXP2F(sacc[n][1]);
      const float p2 = EXP2F(sacc[n][2]), p3 = EXP2F(sacc[n][3]);
      rsn[n] += (p0 + p1) + (p2 + p3);
      union { __hip_bfloat162 hh; unsigned u; } lo, hi;
      lo.hh = __float22bfloat162_rn(make_float2(p0, p1));
      hi.hh = __float22bfloat162_rn(make_float2(p2, p3));
      union { uint2 u2; bf16x4 v; } pk;
      pk.u2 = make_uint2(lo.u, hi.u);
      pf[n] = pk.v;
    }

    // PV: Ot[d][qrow] += V^T[:, wave's keys] @ P  (K=16 MFMA)
    bf16x4 vf[4];
#pragma unroll
    for (int mt = 0; mt < 4; mt++)
      vf[mt] = *(const bf16x4*)(Vc + (uint32_t)(mt * 16 + r16) * 64 + vcol);
    __builtin_amdgcn_s_setprio(1);
#pragma unroll
    for (int mt = 0; mt < 4; mt++)
#pragma unroll
      for (int n = 0; n < 4; n++)
        acc[mt][n] = mfma16(vf[mt], pf[n], acc[mt][n]);
    __builtin_amdgcn_s_setprio(0);

    asm volatile("s_barrier" ::: "memory");  // license re-stage of buf[cur]
  }

  // ---- in-wave quad combine of rowsums (same qrow, different keys) ----
#pragma unroll
  for (int n = 0; n < 4; n++) {
    float r = rsn[n];
    r += __shfl_xor(r, 16, 64);
    r += __shfl_xor(r, 32, 64);
    rsn[n] = r;
  }

  // ---- cross-wave tree reduction through LDS (padded 68-f32 rows) ----
  float* red = (float*)smem;
  __syncthreads();
  if (wid & 2) {  // waves 2,3 -> slots 0,1
    float* p = red + (size_t)(wid & 1) * (64 * 68) + (size_t)lane * 68;
#pragma unroll
    for (int mt = 0; mt < 4; mt++)
#pragma unroll
      for (int n = 0; n < 4; n++)
        *(f32x4*)(p + (mt * 4 + n) * 4) = acc[mt][n];
    p[64] = rsn[0]; p[65] = rsn[1]; p[66] = rsn[2]; p[67] = rsn[3];
  }
  __syncthreads();
  if (!(wid & 2)) {  // wave0+=slot0(wave2), wave1+=slot1(wave3)
    const float* p = red + (size_t)wid * (64 * 68) + (size_t)lane * 68;
#pragma unroll
    for (int mt = 0; mt < 4; mt++)
#pragma unroll
      for (int n = 0; n < 4; n++)
        acc[mt][n] += *(const f32x4*)(p + (mt * 4 + n) * 4);
    rsn[0] += p[64]; rsn[1] += p[65]; rsn[2] += p[66]; rsn[3] += p[67];
  }
  __syncthreads();
  if (wid == 1) {
    float* p = red + (size_t)lane * 68;
#pragma unroll
    for (int mt = 0; mt < 4; mt++)
#pragma unroll
      for (int n = 0; n < 4; n++)
        *(f32x4*)(p + (mt * 4 + n) * 4) = acc[mt][n];
    p[64] = rsn[0]; p[65] = rsn[1]; p[66] = rsn[2]; p[67] = rsn[3];
  }
  __syncthreads();
  if (wid == 0) {
    const float* p = red + (size_t)lane * 68;
#pragma unroll
    for (int mt = 0; mt < 4; mt++)
#pragma unroll
      for (int n = 0; n < 4; n++)
        acc[mt][n] += *(const f32x4*)(p + (mt * 4 + n) * 4);
    rsn[0] += p[64]; rsn[1] += p[65]; rsn[2] += p[66]; rsn[3] += p[67];
    float inv[4];
#pragma unroll
    for (int n = 0; n < 4; n++) inv[n] = 1.0f / rsn[n];
    // write X: d = mt*16+quad*4+reg (contiguous reg), qrow = n*16+r16
#pragma unroll
    for (int mt = 0; mt < 4; mt++) {
#pragma unroll
      for (int n = 0; n < 4; n++) {
        ushort4 o;
        o.x = f2bf(acc[mt][n][0] * inv[n]);
        o.y = f2bf(acc[mt][n][1] * inv[n]);
        o.z = f2bf(acc[mt][n][2] * inv[n]);
        o.w = f2bf(acc[mt][n][3] * inv[n]);
        *(ushort4*)(Xp + (size_t)(b * Ss + qt * 64 + n * 16 + r16) * Dd +
                    h * 64 + mt * 16 + quad * 4) = o;
      }
    }
  }
}

// ---------------------------------------------------------------------------
extern "C" void kernel_launch(void* const* d_in, const int* in_sizes, int n_in,
                              void* d_out, int out_size, void* d_ws,
                              size_t ws_size, hipStream_t stream) {
  const float* q  = (const float*)d_in[0];
  const float* k  = (const float*)d_in[1];
  const float* v  = (const float*)d_in[2];
  const float* Wq = (const float*)d_in[3];
  const float* bq = (const float*)d_in[4];
  const float* Wk = (const float*)d_in[5];
  const float* bk = (const float*)d_in[6];
  const float* Wv = (const float*)d_in[7];
  const float* bv = (const float*)d_in[8];
  const float* Wo = (const float*)d_in[9];
  const float* bo = (const float*)d_in[10];

  ushort_t* ws = (ushort_t*)d_ws;
  const size_t MD = (size_t)Mm * Kk;  // 4,194,304
  const size_t KN = (size_t)Kk * Nn;  // 1,048,576
  ushort_t* qkvb = ws;                // 3*MD   bf16 inputs
  ushort_t* Wt   = ws + 3 * MD;       // 4*KN   transposed weights
  ushort_t* QKVp = Wt + 4 * KN;       // 3*MD   Q,K,V projections
  ushort_t* Vtp  = QKVp + 3 * MD;     // MD     V^T per head
  ushort_t* Xp   = qkvb;              // reuse: qkvb dead after QKV GEMMs

  prep<<<dim3(13312), 256, 0, stream>>>(q, k, v, qkvb, Wq, Wk, Wv, Wo, Wt);
  gemm_mfma<128, true><<<dim3(Nn / 128, Mm / 128, 3), 256, 0, stream>>>(
      qkvb, MD, Wt, KN, bq, bk, bv, QKVp, MD, QSCALE);
  transpose_v<<<dim3(Ss / 64, Hh, Bb), 256, 0, stream>>>(QKVp + 2 * MD, Vtp);
  flash_mfma<<<dim3(Ss / 64, Hh, Bb), 256, 0, stream>>>(QKVp, QKVp + MD, Vtp, Xp);
  gemm_mfma<64, false><<<dim3(Nn / 64, Mm / 128, 1), 256, 0, stream>>>(
      Xp, 0, Wt + 3 * KN, 0, bo, bo, bo, d_out, 0, 1.0f);
}